// Round 4
// baseline (1791.541 us; speedup 1.0000x reference)
//
#include <hip/hip_runtime.h>
#include <hip/hip_bf16.h>
#include <stdint.h>

typedef unsigned int uint_t;
typedef unsigned short ushort_t;

#define NN 100000
#define EE 1600000
#define CC 25000
#define DINTER 144
#define NW 19531250u      // bitmap words: 625e6 bits / 32
#define NBLK 2385         // bitmap blocks: ceil(NW / (256*32))

// ---- ws layout in 32-bit words (total 92.3 MB; round-1 behavior proved >=93.7MB exists) ----
#define W_AGG_EA   0u         // f32 [25000*4]
#define W_CNT      100000u    // u32 [25000]
#define W_OFFS     125000u    // u32 [25008] (needs 25001)
#define W_CURSOR   150008u    // u32 [25000]
#define W_NEWPOS   175008u    // f32 [25000*4]
#define W_M1F      275008u    // f32 [131*128] row-major [j][o]
#define W_AGGB     291776u    // bf16[25000*132] = 1,650,000 words
#define W_SSRC     1941776u   // u32 [1600000]
#define W_BITMAP   3541776u   // u32 [19531250]
#define W_BSUMS    23073026u  // u32 [2385]
#define W_BOFFS    23075411u  // u32 [2386]
#define WS_WORDS   23077797u

// ---- out layout in FLOAT32 elements (total 11,300,000) ----
#define O_XNEW  0u
#define O_POS   3200000u
#define O_EI    3275000u
#define O_ATTR  6475000u
#define O_BATCH 11275000u

static __device__ __forceinline__ ushort_t f2bf(float f) {
    union { float f; uint_t i; } v; v.f = f;
    uint_t x = v.i;
    return (ushort_t)((x + 0x7fffu + ((x >> 16) & 1u)) >> 16);  // RNE
}
static __device__ __forceinline__ float bf2f(ushort_t u) {
    union { uint_t i; float f; } v; v.i = ((uint_t)u) << 16; return v.f;
}

// K1: M1f[j][o] = sum_f Wrow_j[f] * Wg[f][o], f32.
// j in [0,128): W_conv[j][16+f]; j in [128,131): W_edge[j-128][16+f].
__global__ void build_m1f(const float* __restrict__ Wconv,
                          const float* __restrict__ Wedge,
                          const float* __restrict__ Wg,
                          float* __restrict__ m1f) {
    int j = blockIdx.x;   // 0..130
    int o = threadIdx.x;  // 0..127
    const float* wrow = (j < 128) ? (Wconv + j * DINTER + 16)
                                  : (Wedge + (j - 128) * DINTER + 16);
    float acc = 0.f;
    for (int f = 0; f < 128; ++f)
        acc += wrow[f] * Wg[f * 128 + o];
    m1f[j * 128 + o] = acc;
}

// K2a: per-edge: count dst-clusters, set enc bit, accumulate edge_attr.
__global__ void edge_pass1(const int* __restrict__ ei, const float* __restrict__ ea,
                           uint_t* __restrict__ cnt, float* __restrict__ agg_ea,
                           uint_t* __restrict__ bitmap) {
    int e = blockIdx.x * 256 + threadIdx.x;
    if (e >= EE) return;
    uint_t src = (uint_t)ei[e];
    uint_t dst = (uint_t)ei[EE + e];
    uint_t c = dst >> 2;
    atomicAdd(&cnt[c], 1u);
    uint_t enc = (src >> 2) * 25000u + c;
    atomicOr(&bitmap[enc >> 5], 1u << (enc & 31u));
    atomicAdd(&agg_ea[c * 4 + 0], ea[e * 3 + 0]);
    atomicAdd(&agg_ea[c * 4 + 1], ea[e * 3 + 1]);
    atomicAdd(&agg_ea[c * 4 + 2], ea[e * 3 + 2]);
}

// Single-block exclusive scan. out[0..n] (out[n]=total), optional copy out2[0..n-1].
__global__ void scan_small(const uint_t* __restrict__ in, uint_t* __restrict__ out,
                           uint_t* __restrict__ out2, int n) {
    __shared__ uint_t part[256];
    int tid = threadIdx.x;
    int per = (n + 255) >> 8;
    int lo = tid * per;
    int hi = lo + per; if (hi > n) hi = n;
    if (lo > n) lo = n;
    uint_t s = 0;
    for (int i = lo; i < hi; ++i) s += in[i];
    part[tid] = s;
    __syncthreads();
    for (int off = 1; off < 256; off <<= 1) {
        uint_t v = (tid >= off) ? part[tid - off] : 0u;
        __syncthreads();
        part[tid] += v;
        __syncthreads();
    }
    uint_t run = part[tid] - s;  // exclusive prefix of this thread's chunk
    for (int i = lo; i < hi; ++i) {
        out[i] = run;
        if (out2) out2[i] = run;
        run += in[i];
    }
    if (tid == 255) out[n] = run;  // total
}

// K2c: place edges into cluster-sorted order (store src node id).
__global__ void edge_place(const int* __restrict__ ei, uint_t* __restrict__ cursor,
                           uint_t* __restrict__ ssrc) {
    int e = blockIdx.x * 256 + threadIdx.x;
    if (e >= EE) return;
    uint_t src = (uint_t)ei[e];
    uint_t dst = (uint_t)ei[EE + e];
    uint_t p = atomicAdd(&cursor[dst >> 2], 1u);
    ssrc[p] = src;
}

// K3: per cluster: new_pos (f32 ws + f32 out), new_batch, agg_ea -> aggb tail.
__global__ void cluster_pass(const float* __restrict__ pos, const int* __restrict__ batch,
                             const float* __restrict__ agg_ea, float* __restrict__ newpos,
                             ushort_t* __restrict__ aggb, float* __restrict__ out) {
    int c = blockIdx.x * 256 + threadIdx.x;
    if (c >= CC) return;
    float px = 0.f, py = 0.f, pz = 0.f;
    for (int j = 0; j < 4; ++j) {
        int n = c * 4 + j;
        px += pos[n * 3 + 0];
        py += pos[n * 3 + 1];
        pz += pos[n * 3 + 2];
    }
    px *= 0.25f; py *= 0.25f; pz *= 0.25f;
    newpos[c * 4 + 0] = px; newpos[c * 4 + 1] = py; newpos[c * 4 + 2] = pz;
    out[O_POS + c * 3 + 0] = px;
    out[O_POS + c * 3 + 1] = py;
    out[O_POS + c * 3 + 2] = pz;
    int b = batch[c * 4];
    b = max(b, batch[c * 4 + 1]);
    b = max(b, batch[c * 4 + 2]);
    b = max(b, batch[c * 4 + 3]);
    out[O_BATCH + c] = (float)b;
    aggb[(size_t)c * 132 + 128] = f2bf(agg_ea[c * 4 + 0]);
    aggb[(size_t)c * 132 + 129] = f2bf(agg_ea[c * 4 + 1]);
    aggb[(size_t)c * 132 + 130] = f2bf(agg_ea[c * 4 + 2]);
    aggb[(size_t)c * 132 + 131] = 0;
}

// K2d: one wave per cluster; accumulate f32 x rows of its edges; write bf16 aggb[0:128).
__global__ void cluster_reduce(const uint_t* __restrict__ offs, const uint_t* __restrict__ ssrc,
                               const float* __restrict__ x, ushort_t* __restrict__ aggb) {
    int wid = (blockIdx.x * 256 + threadIdx.x) >> 6;
    int lane = threadIdx.x & 63;
    if (wid >= CC) return;
    uint_t start = offs[wid], end = offs[wid + 1];
    float a0 = 0.f, a1 = 0.f;
    for (uint_t i = start; i < end; ++i) {
        uint_t s = ssrc[i];
        float2 v = *(const float2*)(x + (size_t)s * 128 + 2 * lane);
        a0 += v.x;
        a1 += v.y;
    }
    uint_t v = (uint_t)f2bf(a0) | ((uint_t)f2bf(a1) << 16);
    *(uint_t*)(aggb + (size_t)wid * 132 + 2 * lane) = v;
}

// K4: x_new[c][o] = 0.25 * sum_{j<131} aggb[c][j] * M1f[j][o].  f32 VALU.
__global__ void gemm_simple(const ushort_t* __restrict__ aggb, const float* __restrict__ m1f,
                            float* __restrict__ out) {
    __shared__ float srow[132];
    int c = blockIdx.x;      // 0..24999
    int o = threadIdx.x;     // 0..127
    const ushort_t* arow = aggb + (size_t)c * 132;
    srow[o] = bf2f(arow[o]);
    if (o < 4) srow[128 + o] = bf2f(arow[128 + o]);
    __syncthreads();
    float acc = 0.f;
    for (int j = 0; j < 131; ++j)
        acc += srow[j] * m1f[j * 128 + o];
    out[O_XNEW + (size_t)c * 128 + o] = 0.25f * acc;
}

// K6a: per-block popcount of 256*32 bitmap words.
__global__ void bitmap_count(const uint_t* __restrict__ bitmap, uint_t* __restrict__ bsums) {
    __shared__ uint_t sh[256];
    int tid = threadIdx.x;
    uint_t base = ((uint_t)blockIdx.x * 256u + (uint_t)tid) * 32u;
    uint_t s = 0;
    for (int j = 0; j < 32; ++j) {
        uint_t w = base + (uint_t)j;
        if (w < NW) s += __popc(bitmap[w]);
    }
    sh[tid] = s;
    __syncthreads();
    for (int off = 128; off; off >>= 1) {
        if (tid < off) sh[tid] += sh[tid + off];
        __syncthreads();
    }
    if (tid == 0) bsums[blockIdx.x] = sh[0];
}

// K6c: emit sorted unique encs (decoded) + new_edge_attr at their global ranks.
__global__ void bitmap_emit(const uint_t* __restrict__ bitmap, const uint_t* __restrict__ boffs,
                            const float* __restrict__ newpos, float* __restrict__ out) {
    __shared__ uint_t sh[256];
    int tid = threadIdx.x;
    uint_t base = ((uint_t)blockIdx.x * 256u + (uint_t)tid) * 32u;
    uint_t mine = 0;
    for (int j = 0; j < 32; ++j) {
        uint_t w = base + (uint_t)j;
        if (w < NW) mine += __popc(bitmap[w]);
    }
    sh[tid] = mine;
    __syncthreads();
    for (int off = 1; off < 256; off <<= 1) {
        uint_t v = (tid >= off) ? sh[tid - off] : 0u;
        __syncthreads();
        sh[tid] += v;
        __syncthreads();
    }
    uint_t rank = boffs[blockIdx.x] + sh[tid] - mine;
    for (int j = 0; j < 32; ++j) {
        uint_t w = base + (uint_t)j;
        if (w >= NW) break;
        uint_t bits = bitmap[w];
        while (bits) {
            int b = __builtin_ctz(bits);
            bits &= bits - 1u;
            uint_t enc = w * 32u + (uint_t)b;
            uint_t u = enc / 25000u;
            uint_t v = enc - u * 25000u;
            out[O_EI + rank] = (float)u;
            out[O_EI + EE + rank] = (float)v;
            out[O_ATTR + (size_t)rank * 3 + 0] = newpos[v * 4 + 0] - newpos[u * 4 + 0];
            out[O_ATTR + (size_t)rank * 3 + 1] = newpos[v * 4 + 1] - newpos[u * 4 + 1];
            out[O_ATTR + (size_t)rank * 3 + 2] = newpos[v * 4 + 2] - newpos[u * 4 + 2];
            rank++;
        }
    }
}

extern "C" void kernel_launch(void* const* d_in, const int* in_sizes, int n_in,
                              void* d_out, int out_size, void* d_ws, size_t ws_size,
                              hipStream_t stream) {
    const float* x     = (const float*)d_in[0];
    const float* pos   = (const float*)d_in[1];
    const int*   ei    = (const int*)d_in[2];
    const float* ea    = (const float*)d_in[3];
    const int*   batch = (const int*)d_in[4];
    const float* Wconv = (const float*)d_in[5];
    const float* Wedge = (const float*)d_in[6];
    // d_in[7] = D_bloom: dead (bloom_pos never reaches an output)
    const float* Wg    = (const float*)d_in[8];
    // d_in[9] = W_gattr: contribution cancels exactly within each cluster

    float*  out = (float*)d_out;
    uint_t* ws  = (uint_t*)d_ws;

    if (ws_size < (size_t)WS_WORDS * 4) return;

    float*    agg_ea = (float*)(ws + W_AGG_EA);
    uint_t*   cnt    = ws + W_CNT;
    uint_t*   offs   = ws + W_OFFS;
    uint_t*   cursor = ws + W_CURSOR;
    float*    newpos = (float*)(ws + W_NEWPOS);
    float*    m1f    = (float*)(ws + W_M1F);
    ushort_t* aggb   = (ushort_t*)(ws + W_AGGB);
    uint_t*   ssrc   = ws + W_SSRC;
    uint_t*   bitmap = ws + W_BITMAP;
    uint_t*   bsums  = ws + W_BSUMS;
    uint_t*   boffs  = ws + W_BOFFS;

    // zero: agg_ea + cnt (contiguous), bitmap, and the padded tail of ei/attr outputs (f32!)
    hipMemsetAsync(ws, 0, (size_t)(100000 + 25000) * 4, stream);
    hipMemsetAsync(bitmap, 0, (size_t)NW * 4, stream);
    hipMemsetAsync((char*)d_out + (size_t)O_EI * 4, 0, (size_t)(3200000 + 4800000) * 4, stream);

    build_m1f<<<dim3(131), dim3(128), 0, stream>>>(Wconv, Wedge, Wg, m1f);
    edge_pass1<<<dim3(6250), dim3(256), 0, stream>>>(ei, ea, cnt, agg_ea, bitmap);
    scan_small<<<dim3(1), dim3(256), 0, stream>>>(cnt, offs, cursor, CC);
    edge_place<<<dim3(6250), dim3(256), 0, stream>>>(ei, cursor, ssrc);
    cluster_pass<<<dim3(98), dim3(256), 0, stream>>>(pos, batch, agg_ea, newpos, aggb, out);
    cluster_reduce<<<dim3(6250), dim3(256), 0, stream>>>(offs, ssrc, x, aggb);
    gemm_simple<<<dim3(CC), dim3(128), 0, stream>>>(aggb, m1f, out);
    bitmap_count<<<dim3(NBLK), dim3(256), 0, stream>>>(bitmap, bsums);
    scan_small<<<dim3(1), dim3(256), 0, stream>>>(bsums, boffs, (uint_t*)0, NBLK);
    bitmap_emit<<<dim3(NBLK), dim3(256), 0, stream>>>(bitmap, boffs, newpos, out);
}

// Round 5
// 1140.424 us; speedup vs baseline: 1.5709x; 1.5709x over previous
//
#include <hip/hip_runtime.h>
#include <hip/hip_bf16.h>
#include <stdint.h>

typedef unsigned int uint_t;
typedef unsigned short ushort_t;

#define NN 100000
#define EE 1600000
#define CC 25000
#define DINTER 144
#define NW 19531250u      // bitmap words: 625e6 bits / 32
#define NBLK 2385         // bitmap blocks: ceil(NW / 8192)

// ---- ws layout in 32-bit words ----
#define W_AGG_EA   0u         // f32 [25000*4]
#define W_CNT      100000u    // u32 [25000]
#define W_OFFS     125000u    // u32 [25008] (needs 25001)
#define W_CURSOR   150008u    // u32 [25000]
#define W_NEWPOS   175008u    // f32 [25000*4]
#define W_M1F      275008u    // f32 [131*128] row-major [j][o]
#define W_AGGB     291776u    // bf16[25000*132] = 1,650,000 words
#define W_SSRC     1941776u   // u32 [1600000]
#define W_BITMAP   3541776u   // u32 [19531250]
#define W_BSUMS    23073026u  // u32 [2385]
#define W_BOFFS    23075411u  // u32 [2386]
#define WS_WORDS   23077797u

// ---- out layout in FLOAT32 elements (total 11,300,000) ----
#define O_XNEW  0u
#define O_POS   3200000u
#define O_EI    3275000u
#define O_ATTR  6475000u
#define O_BATCH 11275000u

static __device__ __forceinline__ ushort_t f2bf(float f) {
    union { float f; uint_t i; } v; v.f = f;
    uint_t x = v.i;
    return (ushort_t)((x + 0x7fffu + ((x >> 16) & 1u)) >> 16);  // RNE
}
static __device__ __forceinline__ float bf2f(ushort_t u) {
    union { uint_t i; float f; } v; v.i = ((uint_t)u) << 16; return v.f;
}

// K1: M1f[j][o] = sum_f Wrow_j[f] * Wg[f][o], f32.
__global__ void build_m1f(const float* __restrict__ Wconv,
                          const float* __restrict__ Wedge,
                          const float* __restrict__ Wg,
                          float* __restrict__ m1f) {
    int j = blockIdx.x;   // 0..130
    int o = threadIdx.x;  // 0..127
    const float* wrow = (j < 128) ? (Wconv + j * DINTER + 16)
                                  : (Wedge + (j - 128) * DINTER + 16);
    float acc = 0.f;
    for (int f = 0; f < 128; ++f)
        acc += wrow[f] * Wg[f * 128 + o];
    m1f[j * 128 + o] = acc;
}

// K2a: per-edge: count dst-clusters, set enc bit, accumulate edge_attr.
__global__ void edge_pass1(const int* __restrict__ ei, const float* __restrict__ ea,
                           uint_t* __restrict__ cnt, float* __restrict__ agg_ea,
                           uint_t* __restrict__ bitmap) {
    int e = blockIdx.x * 256 + threadIdx.x;
    if (e >= EE) return;
    uint_t src = (uint_t)ei[e];
    uint_t dst = (uint_t)ei[EE + e];
    uint_t c = dst >> 2;
    atomicAdd(&cnt[c], 1u);
    uint_t enc = (src >> 2) * 25000u + c;
    atomicOr(&bitmap[enc >> 5], 1u << (enc & 31u));
    atomicAdd(&agg_ea[c * 4 + 0], ea[e * 3 + 0]);
    atomicAdd(&agg_ea[c * 4 + 1], ea[e * 3 + 1]);
    atomicAdd(&agg_ea[c * 4 + 2], ea[e * 3 + 2]);
}

// Single-block exclusive scan. out[0..n] (out[n]=total), optional copy out2[0..n-1].
__global__ void scan_small(const uint_t* __restrict__ in, uint_t* __restrict__ out,
                           uint_t* __restrict__ out2, int n) {
    __shared__ uint_t part[256];
    int tid = threadIdx.x;
    int per = (n + 255) >> 8;
    int lo = tid * per;
    int hi = lo + per; if (hi > n) hi = n;
    if (lo > n) lo = n;
    uint_t s = 0;
    for (int i = lo; i < hi; ++i) s += in[i];
    part[tid] = s;
    __syncthreads();
    for (int off = 1; off < 256; off <<= 1) {
        uint_t v = (tid >= off) ? part[tid - off] : 0u;
        __syncthreads();
        part[tid] += v;
        __syncthreads();
    }
    uint_t run = part[tid] - s;
    for (int i = lo; i < hi; ++i) {
        out[i] = run;
        if (out2) out2[i] = run;
        run += in[i];
    }
    if (tid == 255) out[n] = run;
}

// K2c: place edges into cluster-sorted order (store src node id).
__global__ void edge_place(const int* __restrict__ ei, uint_t* __restrict__ cursor,
                           uint_t* __restrict__ ssrc) {
    int e = blockIdx.x * 256 + threadIdx.x;
    if (e >= EE) return;
    uint_t src = (uint_t)ei[e];
    uint_t dst = (uint_t)ei[EE + e];
    uint_t p = atomicAdd(&cursor[dst >> 2], 1u);
    ssrc[p] = src;
}

// K3: per cluster: new_pos (f32 ws + f32 out), new_batch, agg_ea -> aggb tail.
__global__ void cluster_pass(const float* __restrict__ pos, const int* __restrict__ batch,
                             const float* __restrict__ agg_ea, float* __restrict__ newpos,
                             ushort_t* __restrict__ aggb, float* __restrict__ out) {
    int c = blockIdx.x * 256 + threadIdx.x;
    if (c >= CC) return;
    float px = 0.f, py = 0.f, pz = 0.f;
    for (int j = 0; j < 4; ++j) {
        int n = c * 4 + j;
        px += pos[n * 3 + 0];
        py += pos[n * 3 + 1];
        pz += pos[n * 3 + 2];
    }
    px *= 0.25f; py *= 0.25f; pz *= 0.25f;
    newpos[c * 4 + 0] = px; newpos[c * 4 + 1] = py; newpos[c * 4 + 2] = pz;
    out[O_POS + c * 3 + 0] = px;
    out[O_POS + c * 3 + 1] = py;
    out[O_POS + c * 3 + 2] = pz;
    int b = batch[c * 4];
    b = max(b, batch[c * 4 + 1]);
    b = max(b, batch[c * 4 + 2]);
    b = max(b, batch[c * 4 + 3]);
    out[O_BATCH + c] = (float)b;
    aggb[(size_t)c * 132 + 128] = f2bf(agg_ea[c * 4 + 0]);
    aggb[(size_t)c * 132 + 129] = f2bf(agg_ea[c * 4 + 1]);
    aggb[(size_t)c * 132 + 130] = f2bf(agg_ea[c * 4 + 2]);
    aggb[(size_t)c * 132 + 131] = 0;
}

// K2d: one wave per cluster; accumulate f32 x rows of its edges; write bf16 aggb[0:128).
__global__ void cluster_reduce(const uint_t* __restrict__ offs, const uint_t* __restrict__ ssrc,
                               const float* __restrict__ x, ushort_t* __restrict__ aggb) {
    int wid = (blockIdx.x * 256 + threadIdx.x) >> 6;
    int lane = threadIdx.x & 63;
    if (wid >= CC) return;
    uint_t start = offs[wid], end = offs[wid + 1];
    float a0 = 0.f, a1 = 0.f;
    for (uint_t i = start; i < end; ++i) {
        uint_t s = ssrc[i];
        float2 v = *(const float2*)(x + (size_t)s * 128 + 2 * lane);
        a0 += v.x;
        a1 += v.y;
    }
    uint_t v = (uint_t)f2bf(a0) | ((uint_t)f2bf(a1) << 16);
    *(uint_t*)(aggb + (size_t)wid * 132 + 2 * lane) = v;
}

// K4: x_new[c][o] = 0.25 * sum_{j<131} aggb[c][j] * M1f[j][o].
// 256 blocks; M1 staged once per block in LDS (bf16); 2 clusters per iteration.
__global__ void gemm_tiled(const ushort_t* __restrict__ aggb, const float* __restrict__ m1f,
                           float* __restrict__ out) {
    __shared__ ushort_t m1s[131 * 128];   // 33.5 KB bf16
    __shared__ float srow[2][132];
    int tid = threadIdx.x;
    for (int i = tid; i < 131 * 128; i += 256) m1s[i] = f2bf(m1f[i]);
    __syncthreads();
    int half = tid >> 7, o = tid & 127;
    int c0 = blockIdx.x * 98;                    // 256*98 = 25088 >= 25000
    for (int it = 0; it < 49; ++it) {
        int c = c0 + it * 2 + half;
        if (c < CC) {
            const ushort_t* ar = aggb + (size_t)c * 132;
            srow[half][o] = bf2f(ar[o]);
            if (o < 4) srow[half][128 + o] = bf2f(ar[128 + o]);
        }
        __syncthreads();
        if (c < CC) {
            float acc = 0.f;
            #pragma unroll 4
            for (int j = 0; j < 131; ++j)
                acc += srow[half][j] * bf2f(m1s[j * 128 + o]);
            out[O_XNEW + (size_t)c * 128 + o] = 0.25f * acc;
        }
        __syncthreads();
    }
}

// K6a: per-block popcount of 8192 bitmap words — coalesced uint4 reads (order-free).
__global__ void bitmap_count(const uint_t* __restrict__ bitmap, uint_t* __restrict__ bsums) {
    __shared__ uint_t sh[256];
    int tid = threadIdx.x;
    uint_t B = (uint_t)blockIdx.x * 8192u;
    uint_t s = 0;
    for (int j = 0; j < 8; ++j) {
        uint_t w = B + (uint_t)j * 1024u + (uint_t)tid * 4u;
        if (w + 3u < NW) {
            uint4 v = *(const uint4*)(bitmap + w);
            s += __popc(v.x) + __popc(v.y) + __popc(v.z) + __popc(v.w);
        } else {
            for (int k = 0; k < 4; ++k)
                if (w + (uint_t)k < NW) s += __popc(bitmap[w + k]);
        }
    }
    sh[tid] = s;
    __syncthreads();
    for (int off = 128; off; off >>= 1) {
        if (tid < off) sh[tid] += sh[tid + off];
        __syncthreads();
    }
    if (tid == 0) bsums[blockIdx.x] = sh[0];
}

// K6c: coalesced-load bitmap into padded LDS, then per-thread 32-consecutive-word emit.
// LDS row r (32 words of global chunk r) lives at lds[r*33 .. r*33+31] — the +1 pad
// makes both the store (phase A) and load (phase B) patterns 2-way-per-bank (free).
__global__ void bitmap_emit(const uint_t* __restrict__ bitmap, const uint_t* __restrict__ boffs,
                            const float* __restrict__ newpos, float* __restrict__ out) {
    __shared__ uint_t lds[256 * 33];
    __shared__ uint_t sh[256];
    int tid = threadIdx.x;
    uint_t B = (uint_t)blockIdx.x * 8192u;
    // Phase A: coalesced uint4 global reads -> padded LDS
    for (int j = 0; j < 8; ++j) {
        uint_t g = (uint_t)j * 1024u + (uint_t)tid * 4u;   // word offset in block
        uint_t w = B + g;
        uint4 v;
        if (w + 3u < NW) {
            v = *(const uint4*)(bitmap + w);
        } else {
            v.x = (w < NW) ? bitmap[w] : 0u;
            v.y = (w + 1u < NW) ? bitmap[w + 1u] : 0u;
            v.z = (w + 2u < NW) ? bitmap[w + 2u] : 0u;
            v.w = (w + 3u < NW) ? bitmap[w + 3u] : 0u;
        }
        uint_t row = g >> 5, col = g & 31u;   // col <= 28, no row wrap
        uint_t a = row * 33u + col;
        lds[a] = v.x; lds[a + 1u] = v.y; lds[a + 2u] = v.z; lds[a + 3u] = v.w;
    }
    __syncthreads();
    // Phase B: per-thread popcount over its 32 consecutive words (from LDS)
    uint_t mine = 0;
    for (int j = 0; j < 32; ++j) mine += __popc(lds[tid * 33 + j]);
    sh[tid] = mine;
    __syncthreads();
    for (int off = 1; off < 256; off <<= 1) {
        uint_t v = (tid >= off) ? sh[tid - off] : 0u;
        __syncthreads();
        sh[tid] += v;
        __syncthreads();
    }
    uint_t rank = boffs[blockIdx.x] + sh[tid] - mine;
    uint_t wbase = B + (uint_t)tid * 32u;
    for (int j = 0; j < 32; ++j) {
        uint_t bits = lds[tid * 33 + j];
        uint_t w = wbase + (uint_t)j;
        while (bits) {
            int b = __builtin_ctz(bits);
            bits &= bits - 1u;
            uint_t enc = w * 32u + (uint_t)b;
            uint_t u = enc / 25000u;
            uint_t v = enc - u * 25000u;
            out[O_EI + rank] = (float)u;
            out[O_EI + EE + rank] = (float)v;
            out[O_ATTR + (size_t)rank * 3 + 0] = newpos[v * 4 + 0] - newpos[u * 4 + 0];
            out[O_ATTR + (size_t)rank * 3 + 1] = newpos[v * 4 + 1] - newpos[u * 4 + 1];
            out[O_ATTR + (size_t)rank * 3 + 2] = newpos[v * 4 + 2] - newpos[u * 4 + 2];
            rank++;
        }
    }
}

extern "C" void kernel_launch(void* const* d_in, const int* in_sizes, int n_in,
                              void* d_out, int out_size, void* d_ws, size_t ws_size,
                              hipStream_t stream) {
    const float* x     = (const float*)d_in[0];
    const float* pos   = (const float*)d_in[1];
    const int*   ei    = (const int*)d_in[2];
    const float* ea    = (const float*)d_in[3];
    const int*   batch = (const int*)d_in[4];
    const float* Wconv = (const float*)d_in[5];
    const float* Wedge = (const float*)d_in[6];
    // d_in[7] = D_bloom: dead (bloom_pos never reaches an output)
    const float* Wg    = (const float*)d_in[8];
    // d_in[9] = W_gattr: contribution cancels exactly within each cluster

    float*  out = (float*)d_out;
    uint_t* ws  = (uint_t*)d_ws;

    if (ws_size < (size_t)WS_WORDS * 4) return;

    float*    agg_ea = (float*)(ws + W_AGG_EA);
    uint_t*   cnt    = ws + W_CNT;
    uint_t*   offs   = ws + W_OFFS;
    uint_t*   cursor = ws + W_CURSOR;
    float*    newpos = (float*)(ws + W_NEWPOS);
    float*    m1f    = (float*)(ws + W_M1F);
    ushort_t* aggb   = (ushort_t*)(ws + W_AGGB);
    uint_t*   ssrc   = ws + W_SSRC;
    uint_t*   bitmap = ws + W_BITMAP;
    uint_t*   bsums  = ws + W_BSUMS;
    uint_t*   boffs  = ws + W_BOFFS;

    hipMemsetAsync(ws, 0, (size_t)(100000 + 25000) * 4, stream);
    hipMemsetAsync(bitmap, 0, (size_t)NW * 4, stream);
    hipMemsetAsync((char*)d_out + (size_t)O_EI * 4, 0, (size_t)(3200000 + 4800000) * 4, stream);

    build_m1f<<<dim3(131), dim3(128), 0, stream>>>(Wconv, Wedge, Wg, m1f);
    edge_pass1<<<dim3(6250), dim3(256), 0, stream>>>(ei, ea, cnt, agg_ea, bitmap);
    scan_small<<<dim3(1), dim3(256), 0, stream>>>(cnt, offs, cursor, CC);
    edge_place<<<dim3(6250), dim3(256), 0, stream>>>(ei, cursor, ssrc);
    cluster_pass<<<dim3(98), dim3(256), 0, stream>>>(pos, batch, agg_ea, newpos, aggb, out);
    cluster_reduce<<<dim3(6250), dim3(256), 0, stream>>>(offs, ssrc, x, aggb);
    gemm_tiled<<<dim3(256), dim3(256), 0, stream>>>(aggb, m1f, out);
    bitmap_count<<<dim3(NBLK), dim3(256), 0, stream>>>(bitmap, bsums);
    scan_small<<<dim3(1), dim3(256), 0, stream>>>(bsums, boffs, (uint_t*)0, NBLK);
    bitmap_emit<<<dim3(NBLK), dim3(256), 0, stream>>>(bitmap, boffs, newpos, out);
}

// Round 6
// 1016.373 us; speedup vs baseline: 1.7627x; 1.1221x over previous
//
#include <hip/hip_runtime.h>
#include <hip/hip_bf16.h>
#include <stdint.h>

typedef unsigned int uint_t;
typedef unsigned short ushort_t;

#define NN 100000
#define EE 1600000
#define CC 25000
#define DINTER 144
#define NW 19531250u      // bitmap words: 625e6 bits / 32
#define NBLK 2385         // bitmap blocks: ceil(NW / 8192)

// ---- ws layout in 32-bit words ----
#define W_AGG_EA   0u         // (unused this round)
#define W_CNT      100000u    // u32 [25000]
#define W_OFFS     125000u    // u32 [25008] (needs 25001)
#define W_CURSOR   150008u    // u32 [25000]
#define W_NEWPOS   175008u    // f32 [25000*4]
#define W_M1F      275008u    // f32 [131*128] row-major [j][o]
#define W_AGGB     291776u    // bf16[25000*132] = 1,650,000 words
#define W_SSRC     1941776u   // u32 [1600000]  (holds EDGE IDS this round)
#define W_BITMAP   3541776u   // u32 [19531250]
#define W_BSUMS    23073026u  // u32 [2385]
#define W_BOFFS    23075411u  // u32 [2386]
#define WS_WORDS   23077797u

// ---- out layout in FLOAT32 elements (total 11,300,000) ----
#define O_XNEW  0u
#define O_POS   3200000u
#define O_EI    3275000u
#define O_ATTR  6475000u
#define O_BATCH 11275000u

static __device__ __forceinline__ ushort_t f2bf(float f) {
    union { float f; uint_t i; } v; v.f = f;
    uint_t x = v.i;
    return (ushort_t)((x + 0x7fffu + ((x >> 16) & 1u)) >> 16);  // RNE
}
static __device__ __forceinline__ float bf2f(ushort_t u) {
    union { uint_t i; float f; } v; v.i = ((uint_t)u) << 16; return v.f;
}

// K1: M1f[j][o] = sum_f Wrow_j[f] * Wg[f][o], f32.
__global__ void build_m1f(const float* __restrict__ Wconv,
                          const float* __restrict__ Wedge,
                          const float* __restrict__ Wg,
                          float* __restrict__ m1f) {
    int j = blockIdx.x;   // 0..130
    int o = threadIdx.x;  // 0..127
    const float* wrow = (j < 128) ? (Wconv + j * DINTER + 16)
                                  : (Wedge + (j - 128) * DINTER + 16);
    float acc = 0.f;
    for (int f = 0; f < 128; ++f)
        acc += wrow[f] * Wg[f * 128 + o];
    m1f[j * 128 + o] = acc;
}

// K2a: per-edge: count dst-clusters + set enc bit. (agg_ea atomics removed — folded
// into cluster_reduce; cuts atomic traffic from 8M to 3.2M ops.)
__global__ void edge_pass1(const int* __restrict__ ei,
                           uint_t* __restrict__ cnt, uint_t* __restrict__ bitmap) {
    int e = blockIdx.x * 256 + threadIdx.x;
    if (e >= EE) return;
    uint_t src = (uint_t)ei[e];
    uint_t dst = (uint_t)ei[EE + e];
    uint_t c = dst >> 2;
    atomicAdd(&cnt[c], 1u);
    uint_t enc = (src >> 2) * 25000u + c;
    atomicOr(&bitmap[enc >> 5], 1u << (enc & 31u));
}

// Single-block exclusive scan. out[0..n] (out[n]=total), optional copy out2[0..n-1].
__global__ void scan_small(const uint_t* __restrict__ in, uint_t* __restrict__ out,
                           uint_t* __restrict__ out2, int n) {
    __shared__ uint_t part[256];
    int tid = threadIdx.x;
    int per = (n + 255) >> 8;
    int lo = tid * per;
    int hi = lo + per; if (hi > n) hi = n;
    if (lo > n) lo = n;
    uint_t s = 0;
    for (int i = lo; i < hi; ++i) s += in[i];
    part[tid] = s;
    __syncthreads();
    for (int off = 1; off < 256; off <<= 1) {
        uint_t v = (tid >= off) ? part[tid - off] : 0u;
        __syncthreads();
        part[tid] += v;
        __syncthreads();
    }
    uint_t run = part[tid] - s;
    for (int i = lo; i < hi; ++i) {
        out[i] = run;
        if (out2) out2[i] = run;
        run += in[i];
    }
    if (tid == 255) out[n] = run;
}

// K2c: place edges into cluster-sorted order (store EDGE ID).
__global__ void edge_place(const int* __restrict__ ei, uint_t* __restrict__ cursor,
                           uint_t* __restrict__ sedge) {
    int e = blockIdx.x * 256 + threadIdx.x;
    if (e >= EE) return;
    uint_t dst = (uint_t)ei[EE + e];
    uint_t p = atomicAdd(&cursor[dst >> 2], 1u);
    sedge[p] = (uint_t)e;
}

// K3: per cluster: new_pos (f32 ws + f32 out), new_batch.
__global__ void cluster_pass(const float* __restrict__ pos, const int* __restrict__ batch,
                             float* __restrict__ newpos, float* __restrict__ out) {
    int c = blockIdx.x * 256 + threadIdx.x;
    if (c >= CC) return;
    float px = 0.f, py = 0.f, pz = 0.f;
    for (int j = 0; j < 4; ++j) {
        int n = c * 4 + j;
        px += pos[n * 3 + 0];
        py += pos[n * 3 + 1];
        pz += pos[n * 3 + 2];
    }
    px *= 0.25f; py *= 0.25f; pz *= 0.25f;
    newpos[c * 4 + 0] = px; newpos[c * 4 + 1] = py; newpos[c * 4 + 2] = pz;
    out[O_POS + c * 3 + 0] = px;
    out[O_POS + c * 3 + 1] = py;
    out[O_POS + c * 3 + 2] = pz;
    int b = batch[c * 4];
    b = max(b, batch[c * 4 + 1]);
    b = max(b, batch[c * 4 + 2]);
    b = max(b, batch[c * 4 + 3]);
    out[O_BATCH + c] = (float)b;
}

// K2d: one wave per cluster; accumulate f32 x rows + edge_attr of its edges (no atomics).
__global__ void cluster_reduce(const uint_t* __restrict__ offs, const uint_t* __restrict__ sedge,
                               const int* __restrict__ ei, const float* __restrict__ ea,
                               const float* __restrict__ x, ushort_t* __restrict__ aggb) {
    int wid = (blockIdx.x * 256 + threadIdx.x) >> 6;
    int lane = threadIdx.x & 63;
    if (wid >= CC) return;
    uint_t start = offs[wid], end = offs[wid + 1];
    float a0 = 0.f, a1 = 0.f, at = 0.f;
    for (uint_t i = start; i < end; ++i) {
        uint_t e = sedge[i];
        uint_t s = (uint_t)ei[e];                      // wave-uniform broadcast load
        float2 v = *(const float2*)(x + (size_t)s * 128 + 2 * lane);
        a0 += v.x;
        a1 += v.y;
        if (lane < 3) at += ea[e * 3 + lane];
    }
    uint_t v = (uint_t)f2bf(a0) | ((uint_t)f2bf(a1) << 16);
    *(uint_t*)(aggb + (size_t)wid * 132 + 2 * lane) = v;
    if (lane < 3) aggb[(size_t)wid * 132 + 128 + lane] = f2bf(at);
    if (lane == 3) aggb[(size_t)wid * 132 + 131] = 0;
}

// K4: x_new[c][o] = 0.25 * sum_{j<131} aggb[c][j] * M1f[j][o].
__global__ void gemm_tiled(const ushort_t* __restrict__ aggb, const float* __restrict__ m1f,
                           float* __restrict__ out) {
    __shared__ ushort_t m1s[131 * 128];   // 33.5 KB bf16
    __shared__ float srow[2][132];
    int tid = threadIdx.x;
    for (int i = tid; i < 131 * 128; i += 256) m1s[i] = f2bf(m1f[i]);
    __syncthreads();
    int half = tid >> 7, o = tid & 127;
    int c0 = blockIdx.x * 98;                    // 256*98 = 25088 >= 25000
    for (int it = 0; it < 49; ++it) {
        int c = c0 + it * 2 + half;
        if (c < CC) {
            const ushort_t* ar = aggb + (size_t)c * 132;
            srow[half][o] = bf2f(ar[o]);
            if (o < 4) srow[half][128 + o] = bf2f(ar[128 + o]);
        }
        __syncthreads();
        if (c < CC) {
            float acc = 0.f;
            #pragma unroll 4
            for (int j = 0; j < 131; ++j)
                acc += srow[half][j] * bf2f(m1s[j * 128 + o]);
            out[O_XNEW + (size_t)c * 128 + o] = 0.25f * acc;
        }
        __syncthreads();
    }
}

// K6a: per-block popcount of 8192 bitmap words — coalesced uint4 reads.
__global__ void bitmap_count(const uint_t* __restrict__ bitmap, uint_t* __restrict__ bsums) {
    __shared__ uint_t sh[256];
    int tid = threadIdx.x;
    uint_t B = (uint_t)blockIdx.x * 8192u;
    uint_t s = 0;
    for (int j = 0; j < 8; ++j) {
        uint_t w = B + (uint_t)j * 1024u + (uint_t)tid * 4u;
        if (w + 3u < NW) {
            uint4 v = *(const uint4*)(bitmap + w);
            s += __popc(v.x) + __popc(v.y) + __popc(v.z) + __popc(v.w);
        } else {
            for (int k = 0; k < 4; ++k)
                if (w + (uint_t)k < NW) s += __popc(bitmap[w + k]);
        }
    }
    sh[tid] = s;
    __syncthreads();
    for (int off = 128; off; off >>= 1) {
        if (tid < off) sh[tid] += sh[tid + off];
        __syncthreads();
    }
    if (tid == 0) bsums[blockIdx.x] = sh[0];
}

// K6c: coalesced-load bitmap into padded LDS, then per-thread 32-consecutive-word emit.
__global__ void bitmap_emit(const uint_t* __restrict__ bitmap, const uint_t* __restrict__ boffs,
                            const float* __restrict__ newpos, float* __restrict__ out) {
    __shared__ uint_t lds[256 * 33];
    __shared__ uint_t sh[256];
    int tid = threadIdx.x;
    uint_t B = (uint_t)blockIdx.x * 8192u;
    for (int j = 0; j < 8; ++j) {
        uint_t g = (uint_t)j * 1024u + (uint_t)tid * 4u;
        uint_t w = B + g;
        uint4 v;
        if (w + 3u < NW) {
            v = *(const uint4*)(bitmap + w);
        } else {
            v.x = (w < NW) ? bitmap[w] : 0u;
            v.y = (w + 1u < NW) ? bitmap[w + 1u] : 0u;
            v.z = (w + 2u < NW) ? bitmap[w + 2u] : 0u;
            v.w = (w + 3u < NW) ? bitmap[w + 3u] : 0u;
        }
        uint_t row = g >> 5, col = g & 31u;
        uint_t a = row * 33u + col;
        lds[a] = v.x; lds[a + 1u] = v.y; lds[a + 2u] = v.z; lds[a + 3u] = v.w;
    }
    __syncthreads();
    uint_t mine = 0;
    for (int j = 0; j < 32; ++j) mine += __popc(lds[tid * 33 + j]);
    sh[tid] = mine;
    __syncthreads();
    for (int off = 1; off < 256; off <<= 1) {
        uint_t v = (tid >= off) ? sh[tid - off] : 0u;
        __syncthreads();
        sh[tid] += v;
        __syncthreads();
    }
    uint_t rank = boffs[blockIdx.x] + sh[tid] - mine;
    uint_t wbase = B + (uint_t)tid * 32u;
    for (int j = 0; j < 32; ++j) {
        uint_t bits = lds[tid * 33 + j];
        uint_t w = wbase + (uint_t)j;
        while (bits) {
            int b = __builtin_ctz(bits);
            bits &= bits - 1u;
            uint_t enc = w * 32u + (uint_t)b;
            uint_t u = enc / 25000u;
            uint_t v = enc - u * 25000u;
            out[O_EI + rank] = (float)u;
            out[O_EI + EE + rank] = (float)v;
            out[O_ATTR + (size_t)rank * 3 + 0] = newpos[v * 4 + 0] - newpos[u * 4 + 0];
            out[O_ATTR + (size_t)rank * 3 + 1] = newpos[v * 4 + 1] - newpos[u * 4 + 1];
            out[O_ATTR + (size_t)rank * 3 + 2] = newpos[v * 4 + 2] - newpos[u * 4 + 2];
            rank++;
        }
    }
}

extern "C" void kernel_launch(void* const* d_in, const int* in_sizes, int n_in,
                              void* d_out, int out_size, void* d_ws, size_t ws_size,
                              hipStream_t stream) {
    const float* x     = (const float*)d_in[0];
    const float* pos   = (const float*)d_in[1];
    const int*   ei    = (const int*)d_in[2];
    const float* ea    = (const float*)d_in[3];
    const int*   batch = (const int*)d_in[4];
    const float* Wconv = (const float*)d_in[5];
    const float* Wedge = (const float*)d_in[6];
    // d_in[7] = D_bloom: dead (bloom_pos never reaches an output)
    const float* Wg    = (const float*)d_in[8];
    // d_in[9] = W_gattr: contribution cancels exactly within each cluster

    float*  out = (float*)d_out;
    uint_t* ws  = (uint_t*)d_ws;

    if (ws_size < (size_t)WS_WORDS * 4) return;

    uint_t*   cnt    = ws + W_CNT;
    uint_t*   offs   = ws + W_OFFS;
    uint_t*   cursor = ws + W_CURSOR;
    float*    newpos = (float*)(ws + W_NEWPOS);
    float*    m1f    = (float*)(ws + W_M1F);
    ushort_t* aggb   = (ushort_t*)(ws + W_AGGB);
    uint_t*   sedge  = ws + W_SSRC;
    uint_t*   bitmap = ws + W_BITMAP;
    uint_t*   bsums  = ws + W_BSUMS;
    uint_t*   boffs  = ws + W_BOFFS;

    hipMemsetAsync(cnt, 0, (size_t)25000 * 4, stream);
    hipMemsetAsync(bitmap, 0, (size_t)NW * 4, stream);
    hipMemsetAsync((char*)d_out + (size_t)O_EI * 4, 0, (size_t)(3200000 + 4800000) * 4, stream);

    build_m1f<<<dim3(131), dim3(128), 0, stream>>>(Wconv, Wedge, Wg, m1f);
    edge_pass1<<<dim3(6250), dim3(256), 0, stream>>>(ei, cnt, bitmap);
    scan_small<<<dim3(1), dim3(256), 0, stream>>>(cnt, offs, cursor, CC);
    edge_place<<<dim3(6250), dim3(256), 0, stream>>>(ei, cursor, sedge);
    cluster_pass<<<dim3(98), dim3(256), 0, stream>>>(pos, batch, newpos, out);
    cluster_reduce<<<dim3(6250), dim3(256), 0, stream>>>(offs, sedge, ei, ea, x, aggb);
    gemm_tiled<<<dim3(256), dim3(256), 0, stream>>>(aggb, m1f, out);
    bitmap_count<<<dim3(NBLK), dim3(256), 0, stream>>>(bitmap, bsums);
    scan_small<<<dim3(1), dim3(256), 0, stream>>>(bsums, boffs, (uint_t*)0, NBLK);
    bitmap_emit<<<dim3(NBLK), dim3(256), 0, stream>>>(bitmap, boffs, newpos, out);
}

// Round 7
// 898.678 us; speedup vs baseline: 1.9935x; 1.1310x over previous
//
#include <hip/hip_runtime.h>
#include <hip/hip_bf16.h>
#include <stdint.h>

typedef unsigned int uint_t;
typedef unsigned short ushort_t;

#define NN 100000
#define EE 1600000
#define CC 25000
#define DINTER 144
#define NW 19531250u      // bitmap words: 625e6 bits / 32
#define NBLK 2385         // bitmap blocks: ceil(NW / 8192)

// ---- ws layout in 32-bit words ----
#define W_CNT      100000u    // u32 [25000]
#define W_OFFS     125000u    // u32 [25008] (needs 25001)
#define W_CURSOR   150008u    // u32 [25000]
#define W_NEWPOS   175008u    // f32 [25000*4]
#define W_M1F      275008u    // f32 [131*128] row-major [j][o]
#define W_AGGB     291776u    // bf16[25000*132] = 1,650,000 words
#define W_SSRC     1941776u   // u32 [1600000]  (edge ids, cluster-sorted)
#define W_BITMAP   3541776u   // u32 [19531250]
#define W_BSUMS    23073026u  // u32 [2385]
#define W_BOFFS    23075411u  // u32 [2386]
#define WS_WORDS   23077797u

// ---- out layout in FLOAT32 elements (total 11,300,000) ----
#define O_XNEW  0u
#define O_POS   3200000u
#define O_EI    3275000u
#define O_ATTR  6475000u
#define O_BATCH 11275000u
// x_bf16 staging: first 6.4M words of the O_EI region (re-zeroed before bitmap_emit)

static __device__ __forceinline__ uint_t f2bf(float f) {
    union { float f; uint_t i; } v; v.f = f;
    uint_t x = v.i;
    return (x + 0x7fffu + ((x >> 16) & 1u)) >> 16;  // RNE
}
static __device__ __forceinline__ float bf2f(ushort_t u) {
    union { uint_t i; float f; } v; v.i = ((uint_t)u) << 16; return v.f;
}

// K0: pack x (f32) -> bf16x2 words into the output-staging region.
__global__ void xpack(const float4* __restrict__ x4, uint2* __restrict__ xb2) {
    int i = blockIdx.x * 256 + threadIdx.x;
    if (i >= NN * 32) return;            // 12.8M floats / 4
    float4 v = x4[i];
    uint2 r;
    r.x = f2bf(v.x) | (f2bf(v.y) << 16);
    r.y = f2bf(v.z) | (f2bf(v.w) << 16);
    xb2[i] = r;
}

// K1: M1f[j][o] = sum_f Wrow_j[f] * Wg[f][o], f32.
__global__ void build_m1f(const float* __restrict__ Wconv,
                          const float* __restrict__ Wedge,
                          const float* __restrict__ Wg,
                          float* __restrict__ m1f) {
    int j = blockIdx.x;   // 0..130
    int o = threadIdx.x;  // 0..127
    const float* wrow = (j < 128) ? (Wconv + j * DINTER + 16)
                                  : (Wedge + (j - 128) * DINTER + 16);
    float acc = 0.f;
    for (int f = 0; f < 128; ++f)
        acc += wrow[f] * Wg[f * 128 + o];
    m1f[j * 128 + o] = acc;
}

// K2a: per-edge: count dst-clusters + set enc bit.
__global__ void edge_pass1(const int* __restrict__ ei,
                           uint_t* __restrict__ cnt, uint_t* __restrict__ bitmap) {
    int e = blockIdx.x * 256 + threadIdx.x;
    if (e >= EE) return;
    uint_t src = (uint_t)ei[e];
    uint_t dst = (uint_t)ei[EE + e];
    uint_t c = dst >> 2;
    atomicAdd(&cnt[c], 1u);
    uint_t enc = (src >> 2) * 25000u + c;
    atomicOr(&bitmap[enc >> 5], 1u << (enc & 31u));
}

// Single-block exclusive scan. out[0..n] (out[n]=total), optional copy out2[0..n-1].
__global__ void scan_small(const uint_t* __restrict__ in, uint_t* __restrict__ out,
                           uint_t* __restrict__ out2, int n) {
    __shared__ uint_t part[256];
    int tid = threadIdx.x;
    int per = (n + 255) >> 8;
    int lo = tid * per;
    int hi = lo + per; if (hi > n) hi = n;
    if (lo > n) lo = n;
    uint_t s = 0;
    for (int i = lo; i < hi; ++i) s += in[i];
    part[tid] = s;
    __syncthreads();
    for (int off = 1; off < 256; off <<= 1) {
        uint_t v = (tid >= off) ? part[tid - off] : 0u;
        __syncthreads();
        part[tid] += v;
        __syncthreads();
    }
    uint_t run = part[tid] - s;
    for (int i = lo; i < hi; ++i) {
        out[i] = run;
        if (out2) out2[i] = run;
        run += in[i];
    }
    if (tid == 255) out[n] = run;
}

// K2c: place edges into cluster-sorted order (store EDGE ID).
__global__ void edge_place(const int* __restrict__ ei, uint_t* __restrict__ cursor,
                           uint_t* __restrict__ sedge) {
    int e = blockIdx.x * 256 + threadIdx.x;
    if (e >= EE) return;
    uint_t dst = (uint_t)ei[EE + e];
    uint_t p = atomicAdd(&cursor[dst >> 2], 1u);
    sedge[p] = (uint_t)e;
}

// K3: per cluster: new_pos (f32 ws + f32 out), new_batch.
__global__ void cluster_pass(const float* __restrict__ pos, const int* __restrict__ batch,
                             float* __restrict__ newpos, float* __restrict__ out) {
    int c = blockIdx.x * 256 + threadIdx.x;
    if (c >= CC) return;
    float px = 0.f, py = 0.f, pz = 0.f;
    for (int j = 0; j < 4; ++j) {
        int n = c * 4 + j;
        px += pos[n * 3 + 0];
        py += pos[n * 3 + 1];
        pz += pos[n * 3 + 2];
    }
    px *= 0.25f; py *= 0.25f; pz *= 0.25f;
    newpos[c * 4 + 0] = px; newpos[c * 4 + 1] = py; newpos[c * 4 + 2] = pz;
    out[O_POS + c * 3 + 0] = px;
    out[O_POS + c * 3 + 1] = py;
    out[O_POS + c * 3 + 2] = pz;
    int b = batch[c * 4];
    b = max(b, batch[c * 4 + 1]);
    b = max(b, batch[c * 4 + 2]);
    b = max(b, batch[c * 4 + 3]);
    out[O_BATCH + c] = (float)b;
}

// K2d: one wave per cluster. Lanes cooperatively load 64 edge ids + srcs (coalesced /
// 64-wide MLP), broadcast srcs via shfl, gather bf16 x rows (256 B each). Each lane
// privately accumulates its own edges' edge_attr; wave-reduced at the end. No atomics.
__global__ void cluster_reduce(const uint_t* __restrict__ offs, const uint_t* __restrict__ sedge,
                               const int* __restrict__ ei, const float* __restrict__ ea,
                               const uint_t* __restrict__ xb, ushort_t* __restrict__ aggb) {
    int wid = (blockIdx.x * 256 + threadIdx.x) >> 6;
    int lane = threadIdx.x & 63;
    if (wid >= CC) return;
    uint_t start = offs[wid], end = offs[wid + 1];
    float a0 = 0.f, a1 = 0.f, t0 = 0.f, t1 = 0.f, t2 = 0.f;
    for (uint_t base = start; base < end; base += 64u) {
        uint_t idx = base + (uint_t)lane;
        int nm = (int)min(64u, end - base);
        int s = 0;
        if (idx < end) {
            uint_t e = sedge[idx];
            s = ei[e];
            t0 += ea[e * 3 + 0];
            t1 += ea[e * 3 + 1];
            t2 += ea[e * 3 + 2];
        }
        if (nm == 64) {
            #pragma unroll 8
            for (int j = 0; j < 64; ++j) {
                uint_t sj = (uint_t)__shfl(s, j, 64);
                uint_t w = xb[(size_t)sj * 64 + lane];
                a0 += bf2f((ushort_t)(w & 0xffffu));
                a1 += bf2f((ushort_t)(w >> 16));
            }
        } else {
            for (int j = 0; j < nm; ++j) {
                uint_t sj = (uint_t)__shfl(s, j, 64);
                uint_t w = xb[(size_t)sj * 64 + lane];
                a0 += bf2f((ushort_t)(w & 0xffffu));
                a1 += bf2f((ushort_t)(w >> 16));
            }
        }
    }
    uint_t v = f2bf(a0) | (f2bf(a1) << 16);
    *(uint_t*)(aggb + (size_t)wid * 132 + 2 * lane) = v;
    for (int off = 32; off; off >>= 1) {
        t0 += __shfl_down(t0, off, 64);
        t1 += __shfl_down(t1, off, 64);
        t2 += __shfl_down(t2, off, 64);
    }
    if (lane == 0) {
        uint_t w0 = f2bf(t0) | (f2bf(t1) << 16);
        uint_t w1 = f2bf(t2);   // slot 131 = 0
        *(uint_t*)(aggb + (size_t)wid * 132 + 128) = w0;
        *(uint_t*)(aggb + (size_t)wid * 132 + 130) = w1;
    }
}

// K4: x_new[c][o] = 0.25 * sum_{j<131} aggb[c][j] * M1f[j][o].
__global__ void gemm_tiled(const ushort_t* __restrict__ aggb, const float* __restrict__ m1f,
                           float* __restrict__ out) {
    __shared__ ushort_t m1s[131 * 128];   // 33.5 KB bf16
    __shared__ float srow[2][132];
    int tid = threadIdx.x;
    for (int i = tid; i < 131 * 128; i += 256) m1s[i] = (ushort_t)f2bf(m1f[i]);
    __syncthreads();
    int half = tid >> 7, o = tid & 127;
    int c0 = blockIdx.x * 98;                    // 256*98 = 25088 >= 25000
    for (int it = 0; it < 49; ++it) {
        int c = c0 + it * 2 + half;
        if (c < CC) {
            const ushort_t* ar = aggb + (size_t)c * 132;
            srow[half][o] = bf2f(ar[o]);
            if (o < 4) srow[half][128 + o] = bf2f(ar[128 + o]);
        }
        __syncthreads();
        if (c < CC) {
            float acc = 0.f;
            #pragma unroll 4
            for (int j = 0; j < 131; ++j)
                acc += srow[half][j] * bf2f(m1s[j * 128 + o]);
            out[O_XNEW + (size_t)c * 128 + o] = 0.25f * acc;
        }
        __syncthreads();
    }
}

// K6a: per-block popcount of 8192 bitmap words — coalesced uint4 reads.
__global__ void bitmap_count(const uint_t* __restrict__ bitmap, uint_t* __restrict__ bsums) {
    __shared__ uint_t sh[256];
    int tid = threadIdx.x;
    uint_t B = (uint_t)blockIdx.x * 8192u;
    uint_t s = 0;
    for (int j = 0; j < 8; ++j) {
        uint_t w = B + (uint_t)j * 1024u + (uint_t)tid * 4u;
        if (w + 3u < NW) {
            uint4 v = *(const uint4*)(bitmap + w);
            s += __popc(v.x) + __popc(v.y) + __popc(v.z) + __popc(v.w);
        } else {
            for (int k = 0; k < 4; ++k)
                if (w + (uint_t)k < NW) s += __popc(bitmap[w + k]);
        }
    }
    sh[tid] = s;
    __syncthreads();
    for (int off = 128; off; off >>= 1) {
        if (tid < off) sh[tid] += sh[tid + off];
        __syncthreads();
    }
    if (tid == 0) bsums[blockIdx.x] = sh[0];
}

// K6c: coalesced-load bitmap into padded LDS, then per-thread 32-consecutive-word emit.
__global__ void bitmap_emit(const uint_t* __restrict__ bitmap, const uint_t* __restrict__ boffs,
                            const float* __restrict__ newpos, float* __restrict__ out) {
    __shared__ uint_t lds[256 * 33];
    __shared__ uint_t sh[256];
    int tid = threadIdx.x;
    uint_t B = (uint_t)blockIdx.x * 8192u;
    for (int j = 0; j < 8; ++j) {
        uint_t g = (uint_t)j * 1024u + (uint_t)tid * 4u;
        uint_t w = B + g;
        uint4 v;
        if (w + 3u < NW) {
            v = *(const uint4*)(bitmap + w);
        } else {
            v.x = (w < NW) ? bitmap[w] : 0u;
            v.y = (w + 1u < NW) ? bitmap[w + 1u] : 0u;
            v.z = (w + 2u < NW) ? bitmap[w + 2u] : 0u;
            v.w = (w + 3u < NW) ? bitmap[w + 3u] : 0u;
        }
        uint_t row = g >> 5, col = g & 31u;
        uint_t a = row * 33u + col;
        lds[a] = v.x; lds[a + 1u] = v.y; lds[a + 2u] = v.z; lds[a + 3u] = v.w;
    }
    __syncthreads();
    uint_t mine = 0;
    for (int j = 0; j < 32; ++j) mine += __popc(lds[tid * 33 + j]);
    sh[tid] = mine;
    __syncthreads();
    for (int off = 1; off < 256; off <<= 1) {
        uint_t v = (tid >= off) ? sh[tid - off] : 0u;
        __syncthreads();
        sh[tid] += v;
        __syncthreads();
    }
    uint_t rank = boffs[blockIdx.x] + sh[tid] - mine;
    uint_t wbase = B + (uint_t)tid * 32u;
    for (int j = 0; j < 32; ++j) {
        uint_t bits = lds[tid * 33 + j];
        uint_t w = wbase + (uint_t)j;
        while (bits) {
            int b = __builtin_ctz(bits);
            bits &= bits - 1u;
            uint_t enc = w * 32u + (uint_t)b;
            uint_t u = enc / 25000u;
            uint_t v = enc - u * 25000u;
            out[O_EI + rank] = (float)u;
            out[O_EI + EE + rank] = (float)v;
            out[O_ATTR + (size_t)rank * 3 + 0] = newpos[v * 4 + 0] - newpos[u * 4 + 0];
            out[O_ATTR + (size_t)rank * 3 + 1] = newpos[v * 4 + 1] - newpos[u * 4 + 1];
            out[O_ATTR + (size_t)rank * 3 + 2] = newpos[v * 4 + 2] - newpos[u * 4 + 2];
            rank++;
        }
    }
}

extern "C" void kernel_launch(void* const* d_in, const int* in_sizes, int n_in,
                              void* d_out, int out_size, void* d_ws, size_t ws_size,
                              hipStream_t stream) {
    const float* x     = (const float*)d_in[0];
    const float* pos   = (const float*)d_in[1];
    const int*   ei    = (const int*)d_in[2];
    const float* ea    = (const float*)d_in[3];
    const int*   batch = (const int*)d_in[4];
    const float* Wconv = (const float*)d_in[5];
    const float* Wedge = (const float*)d_in[6];
    // d_in[7] = D_bloom: dead (bloom_pos never reaches an output)
    const float* Wg    = (const float*)d_in[8];
    // d_in[9] = W_gattr: contribution cancels exactly within each cluster

    float*  out = (float*)d_out;
    uint_t* ws  = (uint_t*)d_ws;

    if (ws_size < (size_t)WS_WORDS * 4) return;

    uint_t*   cnt    = ws + W_CNT;
    uint_t*   offs   = ws + W_OFFS;
    uint_t*   cursor = ws + W_CURSOR;
    float*    newpos = (float*)(ws + W_NEWPOS);
    float*    m1f    = (float*)(ws + W_M1F);
    ushort_t* aggb   = (ushort_t*)(ws + W_AGGB);
    uint_t*   sedge  = ws + W_SSRC;
    uint_t*   bitmap = ws + W_BITMAP;
    uint_t*   bsums  = ws + W_BSUMS;
    uint_t*   boffs  = ws + W_BOFFS;
    uint_t*   xb     = (uint_t*)(out + O_EI);   // 6.4M-word bf16-x staging in out region

    hipMemsetAsync(cnt, 0, (size_t)25000 * 4, stream);
    hipMemsetAsync(bitmap, 0, (size_t)NW * 4, stream);

    xpack<<<dim3(12500), dim3(256), 0, stream>>>((const float4*)x, (uint2*)xb);
    build_m1f<<<dim3(131), dim3(128), 0, stream>>>(Wconv, Wedge, Wg, m1f);
    edge_pass1<<<dim3(6250), dim3(256), 0, stream>>>(ei, cnt, bitmap);
    scan_small<<<dim3(1), dim3(256), 0, stream>>>(cnt, offs, cursor, CC);
    edge_place<<<dim3(6250), dim3(256), 0, stream>>>(ei, cursor, sedge);
    cluster_pass<<<dim3(98), dim3(256), 0, stream>>>(pos, batch, newpos, out);
    cluster_reduce<<<dim3(6250), dim3(256), 0, stream>>>(offs, sedge, ei, ea, xb, aggb);
    gemm_tiled<<<dim3(256), dim3(256), 0, stream>>>(aggb, m1f, out);
    // x_bf16 staging no longer needed: zero the EI/ATTR region (incl. padding tail)
    hipMemsetAsync((char*)d_out + (size_t)O_EI * 4, 0, (size_t)(3200000 + 4800000) * 4, stream);
    bitmap_count<<<dim3(NBLK), dim3(256), 0, stream>>>(bitmap, bsums);
    scan_small<<<dim3(1), dim3(256), 0, stream>>>(bsums, boffs, (uint_t*)0, NBLK);
    bitmap_emit<<<dim3(NBLK), dim3(256), 0, stream>>>(bitmap, boffs, newpos, out);
}